// Round 7
// baseline (471.194 us; speedup 1.0000x reference)
//
#include <hip/hip_runtime.h>

typedef short v8s __attribute__((ext_vector_type(8)));
typedef _Float16 v8h __attribute__((ext_vector_type(8)));
typedef float v4f __attribute__((ext_vector_type(4)));

typedef __attribute__((address_space(1))) const void* as1_void_cp;
typedef __attribute__((address_space(3))) void* as3_void_p;

__device__ __forceinline__ unsigned short f2bf(float x) {
  union { float f; unsigned int u; } v; v.f = x;
  unsigned int r = v.u + 0x7fffu + ((v.u >> 16) & 1u);
  return (unsigned short)(r >> 16);
}
__device__ __forceinline__ float bf2f(unsigned short h) {
  union { unsigned int u; float f; } v; v.u = ((unsigned int)h) << 16;
  return v.f;
}
__device__ __forceinline__ unsigned short f2h(float x) {
  _Float16 h = (_Float16)x;  // RTE
  return __builtin_bit_cast(unsigned short, h);
}

// XCD-aware bijective block swizzle (T1/m204): each XCD gets a CONTIGUOUS
// chunk of logical tiles -> shared A/B panels fetched once per XCD-L2.
struct B3 { int x, y, z; };
__device__ __forceinline__ B3 xcd_swizzle() {
  const int gx = gridDim.x, gy = gridDim.y;
  const int nwg = gx * gy * gridDim.z;
  int flat = blockIdx.x + gx * (blockIdx.y + gy * blockIdx.z);
  if ((nwg & 7) == 0) flat = (flat & 7) * (nwg >> 3) + (flat >> 3);
  B3 b;
  b.x = flat % gx;
  b.y = (flat / gx) % gy;
  b.z = flat / (gx * gy);
  return b;
}

// ---------------------------------------------------------------------------
// Plain GEMM (bf16 or fp16 per F16): C[MxN](f32) = A[MxK] @ B[NxK]^T.
// 128x128 tile, BK=64. Double-buffered LDS, counted vmcnt, XCD swizzle.
// ---------------------------------------------------------------------------
template <bool ADD, bool F16>
__global__ __launch_bounds__(256) void gemm_bt(
    const unsigned short* __restrict__ A, const unsigned short* __restrict__ B,
    float* __restrict__ C, const float* __restrict__ Cadd,
    int N, int lda, int ldb, int klen, size_t csplit) {
  __shared__ __align__(16) unsigned short As[2][128 * 64];
  __shared__ __align__(16) unsigned short Bs[2][128 * 64];
  const int tid = threadIdx.x;
  const B3 bid = xcd_swizzle();
  const int bn = bid.x * 128, bm = bid.y * 128;
  const int k0 = bid.z * klen;
  float* Cp = C + (size_t)bid.z * csplit;

  const unsigned short* ag0 = A + (size_t)(bm + (tid >> 2)) * lda + ((tid & 3) << 3) + k0;
  const unsigned short* ag1 = ag0 + (size_t)64 * lda;
  const unsigned short* bg0 = B + (size_t)(bn + (tid >> 2)) * ldb + ((tid & 3) << 3) + k0;
  const unsigned short* bg1 = bg0 + (size_t)64 * ldb;

  const int lane = tid & 63;
  const int q = lane >> 4, m15 = lane & 15;
  const int w = tid >> 6;
  const int wr = (w >> 1) * 64, wc = (w & 1) * 64;

  v4f acc[4][4];
#pragma unroll
  for (int i = 0; i < 4; ++i)
#pragma unroll
    for (int j = 0; j < 4; ++j) acc[i][j] = 0.f;

  auto stage = [&](int kk, int b) {
    unsigned short* al = As[b] + tid * 8;
    unsigned short* bl = Bs[b] + tid * 8;
    __builtin_amdgcn_global_load_lds((as1_void_cp)(ag0 + kk), (as3_void_p)al, 16, 0, 0);
    __builtin_amdgcn_global_load_lds((as1_void_cp)(ag1 + kk), (as3_void_p)(al + 2048), 16, 0, 0);
    __builtin_amdgcn_global_load_lds((as1_void_cp)(ag0 + kk + 32), (as3_void_p)(al + 4096), 16, 0, 0);
    __builtin_amdgcn_global_load_lds((as1_void_cp)(ag1 + kk + 32), (as3_void_p)(al + 6144), 16, 0, 0);
    __builtin_amdgcn_global_load_lds((as1_void_cp)(bg0 + kk), (as3_void_p)bl, 16, 0, 0);
    __builtin_amdgcn_global_load_lds((as1_void_cp)(bg1 + kk), (as3_void_p)(bl + 2048), 16, 0, 0);
    __builtin_amdgcn_global_load_lds((as1_void_cp)(bg0 + kk + 32), (as3_void_p)(bl + 4096), 16, 0, 0);
    __builtin_amdgcn_global_load_lds((as1_void_cp)(bg1 + kk + 32), (as3_void_p)(bl + 6144), 16, 0, 0);
  };

  const int nt = klen >> 6;
  stage(0, 0);
  if (nt > 1) stage(64, 1);
  for (int t = 0; t < nt; ++t) {
    if (t + 1 < nt)
      asm volatile("s_waitcnt vmcnt(8)" ::: "memory");
    else
      asm volatile("s_waitcnt vmcnt(0)" ::: "memory");
    __builtin_amdgcn_s_barrier();
    const unsigned short* Ab = As[t & 1];
    const unsigned short* Bb = Bs[t & 1];
#pragma unroll
    for (int h = 0; h < 2; ++h) {
      v8s af[4], bf[4];
#pragma unroll
      for (int i = 0; i < 4; ++i)
        af[i] = *(const v8s*)(Ab + h * 4096 + (wr + i * 16 + m15) * 32 + q * 8);
#pragma unroll
      for (int j = 0; j < 4; ++j)
        bf[j] = *(const v8s*)(Bb + h * 4096 + (wc + j * 16 + m15) * 32 + q * 8);
#pragma unroll
      for (int i = 0; i < 4; ++i)
#pragma unroll
        for (int j = 0; j < 4; ++j) {
          if constexpr (F16)
            acc[i][j] = __builtin_amdgcn_mfma_f32_16x16x32_f16(
                __builtin_bit_cast(v8h, af[i]), __builtin_bit_cast(v8h, bf[j]), acc[i][j], 0, 0, 0);
          else
            acc[i][j] = __builtin_amdgcn_mfma_f32_16x16x32_bf16(af[i], bf[j], acc[i][j], 0, 0, 0);
        }
    }
    if (t + 2 < nt) {
      __builtin_amdgcn_s_barrier();
      stage((t + 2) << 6, t & 1);
    }
  }

#pragma unroll
  for (int i = 0; i < 4; ++i) {
#pragma unroll
    for (int j = 0; j < 4; ++j) {
      const int col = bn + wc + j * 16 + m15;
#pragma unroll
      for (int rr = 0; rr < 4; ++rr) {
        const int row = bm + wr + i * 16 + q * 4 + rr;
        const size_t idx = (size_t)row * N + col;
        float v = acc[i][j][rr];
        if (ADD) v += Cadd[idx];
        Cp[idx] = v;
      }
    }
  }
}

// ---------------------------------------------------------------------------
// Split-bf16 (compensated) GEMM: C = (Ah+Al)@(Bh+Bl)^T dropping Al*Bl.
// EM iteration 1 only. BK=32, dbuf + counted vmcnt + XCD swizzle.
// ---------------------------------------------------------------------------
__global__ __launch_bounds__(256) void gemm_bt3(
    const unsigned short* __restrict__ Ah, const unsigned short* __restrict__ Al,
    const unsigned short* __restrict__ Bh, const unsigned short* __restrict__ Bl,
    float* __restrict__ C, int N, int lda, int ldb, int klen, size_t csplit) {
  __shared__ __align__(16) unsigned short Ash[2][128 * 32];
  __shared__ __align__(16) unsigned short Asl[2][128 * 32];
  __shared__ __align__(16) unsigned short Bsh[2][128 * 32];
  __shared__ __align__(16) unsigned short Bsl[2][128 * 32];
  const int tid = threadIdx.x;
  const B3 bid = xcd_swizzle();
  const int bn = bid.x * 128, bm = bid.y * 128;
  const int k0 = bid.z * klen;
  float* Cp = C + (size_t)bid.z * csplit;

  const size_t aoff = (size_t)(bm + (tid >> 2)) * lda + ((tid & 3) << 3) + k0;
  const size_t boff = (size_t)(bn + (tid >> 2)) * ldb + ((tid & 3) << 3) + k0;
  const unsigned short* agh0 = Ah + aoff;
  const unsigned short* agh1 = agh0 + (size_t)64 * lda;
  const unsigned short* agl0 = Al + aoff;
  const unsigned short* agl1 = agl0 + (size_t)64 * lda;
  const unsigned short* bgh0 = Bh + boff;
  const unsigned short* bgh1 = bgh0 + (size_t)64 * ldb;
  const unsigned short* bgl0 = Bl + boff;
  const unsigned short* bgl1 = bgl0 + (size_t)64 * ldb;

  const int lane = tid & 63;
  const int q = lane >> 4, m15 = lane & 15;
  const int w = tid >> 6;
  const int wr = (w >> 1) * 64, wc = (w & 1) * 64;

  v4f acc[4][4];
#pragma unroll
  for (int i = 0; i < 4; ++i)
#pragma unroll
    for (int j = 0; j < 4; ++j) acc[i][j] = 0.f;

  auto stage = [&](int kk, int b) {
    __builtin_amdgcn_global_load_lds((as1_void_cp)(agh0 + kk), (as3_void_p)(Ash[b] + tid * 8), 16, 0, 0);
    __builtin_amdgcn_global_load_lds((as1_void_cp)(agh1 + kk), (as3_void_p)(Ash[b] + 2048 + tid * 8), 16, 0, 0);
    __builtin_amdgcn_global_load_lds((as1_void_cp)(agl0 + kk), (as3_void_p)(Asl[b] + tid * 8), 16, 0, 0);
    __builtin_amdgcn_global_load_lds((as1_void_cp)(agl1 + kk), (as3_void_p)(Asl[b] + 2048 + tid * 8), 16, 0, 0);
    __builtin_amdgcn_global_load_lds((as1_void_cp)(bgh0 + kk), (as3_void_p)(Bsh[b] + tid * 8), 16, 0, 0);
    __builtin_amdgcn_global_load_lds((as1_void_cp)(bgh1 + kk), (as3_void_p)(Bsh[b] + 2048 + tid * 8), 16, 0, 0);
    __builtin_amdgcn_global_load_lds((as1_void_cp)(bgl0 + kk), (as3_void_p)(Bsl[b] + tid * 8), 16, 0, 0);
    __builtin_amdgcn_global_load_lds((as1_void_cp)(bgl1 + kk), (as3_void_p)(Bsl[b] + 2048 + tid * 8), 16, 0, 0);
  };

  const int nt = klen >> 5;
  stage(0, 0);
  if (nt > 1) stage(32, 1);
  for (int t = 0; t < nt; ++t) {
    if (t + 1 < nt)
      asm volatile("s_waitcnt vmcnt(8)" ::: "memory");
    else
      asm volatile("s_waitcnt vmcnt(0)" ::: "memory");
    __builtin_amdgcn_s_barrier();
    const int b = t & 1;
    v8s afh[4], afl[4], bfh[4], bfl[4];
#pragma unroll
    for (int i = 0; i < 4; ++i) {
      const int ro = (wr + i * 16 + m15) * 32 + q * 8;
      afh[i] = *(const v8s*)(Ash[b] + ro);
      afl[i] = *(const v8s*)(Asl[b] + ro);
    }
#pragma unroll
    for (int j = 0; j < 4; ++j) {
      const int ro = (wc + j * 16 + m15) * 32 + q * 8;
      bfh[j] = *(const v8s*)(Bsh[b] + ro);
      bfl[j] = *(const v8s*)(Bsl[b] + ro);
    }
#pragma unroll
    for (int i = 0; i < 4; ++i)
#pragma unroll
      for (int j = 0; j < 4; ++j) {
        acc[i][j] = __builtin_amdgcn_mfma_f32_16x16x32_bf16(afh[i], bfh[j], acc[i][j], 0, 0, 0);
        acc[i][j] = __builtin_amdgcn_mfma_f32_16x16x32_bf16(afh[i], bfl[j], acc[i][j], 0, 0, 0);
        acc[i][j] = __builtin_amdgcn_mfma_f32_16x16x32_bf16(afl[i], bfh[j], acc[i][j], 0, 0, 0);
      }
    if (t + 2 < nt) {
      __builtin_amdgcn_s_barrier();
      stage((t + 2) << 5, b);
    }
  }

#pragma unroll
  for (int i = 0; i < 4; ++i) {
#pragma unroll
    for (int j = 0; j < 4; ++j) {
      const int col = bn + wc + j * 16 + m15;
#pragma unroll
      for (int rr = 0; rr < 4; ++rr) {
        const int row = bm + wr + i * 16 + q * 4 + rr;
        Cp[(size_t)row * N + col] = acc[i][j][rr];
      }
    }
  }
}

// ---------------------------------------------------------------------------
// Fused S-GEMM + row-softmax (fp16, EM iters 2-5 + final stage).
// Tile = 32 b-rows x ALL 512 c-cols (softmax rows block-local), BK=64.
// 256 thr (4 waves); wave w owns cols [w*128, w*128+128): acc[2][8].
// A (32x64, 4 KB) and B=p (512x64, 64 KB) staged via global_load_lds,
// double-buffered, counted vmcnt(17). LDS 137 KB -> 1 block/CU.
// ---------------------------------------------------------------------------
template <bool FINAL>
__global__ __launch_bounds__(256) void s_softmax_fused(
    const unsigned short* __restrict__ A,   // cls fp16 [8192][1024]
    const unsigned short* __restrict__ B,   // p   fp16 [512][1024]
    unsigned short* __restrict__ rT,        // [512][8192] fp16  (FINAL=0)
    float* __restrict__ r_out,              // [8192][512] f32   (FINAL=1)
    unsigned short* __restrict__ r_row) {   // [8192][512] fp16  (FINAL=1)
  __shared__ __align__(16) unsigned short As[2][32 * 64];
  __shared__ __align__(16) unsigned short Bs[2][512 * 64];
  __shared__ float redm[4][32];
  __shared__ float reds[4][32];
  const int tid = threadIdx.x;
  const int lane = tid & 63;
  const int wv = tid >> 6;
  const int q = lane >> 4, m15 = lane & 15;
  const int wc = wv * 128;
  const int b0 = blockIdx.x * 32;

  const int srow = tid >> 3, scol = (tid & 7) << 3;   // staging: row, col8
  const unsigned short* ag = A + (size_t)(b0 + srow) * 1024 + scol;
  const unsigned short* bg = B + (size_t)srow * 1024 + scol;

  auto stage = [&](int kk, int b) {
    __builtin_amdgcn_global_load_lds((as1_void_cp)(ag + kk), (as3_void_p)(As[b] + tid * 8), 16, 0, 0);
#pragma unroll
    for (int s = 0; s < 16; ++s)
      __builtin_amdgcn_global_load_lds((as1_void_cp)(bg + (size_t)s * 32 * 1024 + kk),
                                       (as3_void_p)(Bs[b] + s * 2048 + tid * 8), 16, 0, 0);
  };

  v4f acc[2][8];
#pragma unroll
  for (int i = 0; i < 2; ++i)
#pragma unroll
    for (int j = 0; j < 8; ++j) acc[i][j] = 0.f;

  stage(0, 0);
  stage(64, 1);
  for (int t = 0; t < 16; ++t) {
    if (t < 15)
      asm volatile("s_waitcnt vmcnt(17)" ::: "memory");
    else
      asm volatile("s_waitcnt vmcnt(0)" ::: "memory");
    __builtin_amdgcn_s_barrier();
    const unsigned short* Ab = As[t & 1];
    const unsigned short* Bb = Bs[t & 1];
#pragma unroll
    for (int h = 0; h < 2; ++h) {
      v8s af[2], bf[8];
#pragma unroll
      for (int i = 0; i < 2; ++i)
        af[i] = *(const v8s*)(Ab + (i * 16 + m15) * 64 + h * 32 + q * 8);
#pragma unroll
      for (int j = 0; j < 8; ++j)
        bf[j] = *(const v8s*)(Bb + (wc + j * 16 + m15) * 64 + h * 32 + q * 8);
#pragma unroll
      for (int i = 0; i < 2; ++i)
#pragma unroll
        for (int j = 0; j < 8; ++j)
          acc[i][j] = __builtin_amdgcn_mfma_f32_16x16x32_f16(
              __builtin_bit_cast(v8h, af[i]), __builtin_bit_cast(v8h, bf[j]), acc[i][j], 0, 0, 0);
    }
    if (t + 2 < 16) {
      __builtin_amdgcn_s_barrier();
      stage((t + 2) << 6, t & 1);
    }
  }

  // ---- row max: in-lane over j, shfl over 16-lane col group, LDS x-wave ---
  float mx[2][4];
#pragma unroll
  for (int i = 0; i < 2; ++i)
#pragma unroll
    for (int rr = 0; rr < 4; ++rr) {
      float m = acc[i][0][rr];
#pragma unroll
      for (int j = 1; j < 8; ++j) m = fmaxf(m, acc[i][j][rr]);
      m = fmaxf(m, __shfl_xor(m, 1));
      m = fmaxf(m, __shfl_xor(m, 2));
      m = fmaxf(m, __shfl_xor(m, 4));
      m = fmaxf(m, __shfl_xor(m, 8));
      mx[i][rr] = m;
    }
  if (m15 == 0) {
#pragma unroll
    for (int i = 0; i < 2; ++i)
#pragma unroll
      for (int rr = 0; rr < 4; ++rr) redm[wv][i * 16 + q * 4 + rr] = mx[i][rr];
  }
  __syncthreads();
#pragma unroll
  for (int i = 0; i < 2; ++i)
#pragma unroll
    for (int rr = 0; rr < 4; ++rr) {
      const int row = i * 16 + q * 4 + rr;
      mx[i][rr] = fmaxf(fmaxf(redm[0][row], redm[1][row]),
                        fmaxf(redm[2][row], redm[3][row]));
    }

  // ---- exp + row sum (overwrite acc) ----
  float sm[2][4];
#pragma unroll
  for (int i = 0; i < 2; ++i)
#pragma unroll
    for (int rr = 0; rr < 4; ++rr) {
      float s = 0.f;
#pragma unroll
      for (int j = 0; j < 8; ++j) {
        const float e = __expf(acc[i][j][rr] - mx[i][rr]);
        acc[i][j][rr] = e;
        s += e;
      }
      s += __shfl_xor(s, 1);
      s += __shfl_xor(s, 2);
      s += __shfl_xor(s, 4);
      s += __shfl_xor(s, 8);
      sm[i][rr] = s;
    }
  if (m15 == 0) {
#pragma unroll
    for (int i = 0; i < 2; ++i)
#pragma unroll
      for (int rr = 0; rr < 4; ++rr) reds[wv][i * 16 + q * 4 + rr] = sm[i][rr];
  }
  __syncthreads();
#pragma unroll
  for (int i = 0; i < 2; ++i)
#pragma unroll
    for (int rr = 0; rr < 4; ++rr) {
      const int row = i * 16 + q * 4 + rr;
      sm[i][rr] = 1.f / (reds[0][row] + reds[1][row] + reds[2][row] + reds[3][row]);
    }

  // ---- normalize + stage fp16 into padded LDS (overlay dead Bs) ----
  unsigned short* th = (unsigned short*)&Bs[0][0];  // 32*520*2 B = 33 KB < 64 KB
#pragma unroll
  for (int i = 0; i < 2; ++i)
#pragma unroll
    for (int j = 0; j < 8; ++j)
#pragma unroll
      for (int rr = 0; rr < 4; ++rr) {
        const float v = acc[i][j][rr] * sm[i][rr];
        const int row = i * 16 + q * 4 + rr;
        const int col = wc + j * 16 + m15;
        th[row * 520 + col] = f2h(v);
        if constexpr (FINAL) r_out[(size_t)(b0 + row) * 512 + col] = v;
      }
  __syncthreads();

  if constexpr (!FINAL) {
    // thread owns c-rows tid and tid+256; 32 b values = 64 B contiguous
#pragma unroll
    for (int cc = 0; cc < 2; ++cc) {
      const int c = tid + cc * 256;
      unsigned short uh[32];
#pragma unroll
      for (int b = 0; b < 32; ++b) uh[b] = th[b * 520 + c];
#pragma unroll
      for (int u = 0; u < 4; ++u)
        *(v8s*)(rT + (size_t)c * 8192 + b0 + u * 8) = *(v8s*)&uh[u * 8];
    }
  } else {
    // row-major fp16 r: thread -> row tid>>3, 64 contiguous cols
    const int row = tid >> 3;
    const int c0 = (tid & 7) * 64;
#pragma unroll
    for (int u = 0; u < 8; ++u)
      *(v8s*)(r_row + (size_t)(b0 + row) * 512 + c0 + u * 8) =
          *(const v8s*)&th[row * 520 + c0 + u * 8];
  }
}

// cls f32 [8192][1024] -> hi/lo bf16 (row + transposed) AND fp16 (row +
// transposed), one pass. fp16 = f2h(hi+lo).
__global__ __launch_bounds__(256) void cast_split_transpose_cls(
    const float* __restrict__ cls,
    unsigned short* __restrict__ ch, unsigned short* __restrict__ cl,
    unsigned short* __restrict__ cTh, unsigned short* __restrict__ cTl,
    unsigned short* __restrict__ cg, unsigned short* __restrict__ cTg) {
  __shared__ unsigned short th[64][72];
  __shared__ unsigned short tl[64][72];
  const int d0 = blockIdx.x * 64, b0 = blockIdx.y * 64;
  const int t = threadIdx.x;
#pragma unroll
  for (int i = 0; i < 4; ++i) {
    int flat = t + i * 256;
    int bl_ = flat >> 4;
    int dl = (flat & 15) << 2;
    float4 v = *(const float4*)(cls + (size_t)(b0 + bl_) * 1024 + d0 + dl);
    ushort4 h, l, g;
    h.x = f2bf(v.x); l.x = f2bf(v.x - bf2f(h.x)); g.x = f2h(bf2f(h.x) + bf2f(l.x));
    h.y = f2bf(v.y); l.y = f2bf(v.y - bf2f(h.y)); g.y = f2h(bf2f(h.y) + bf2f(l.y));
    h.z = f2bf(v.z); l.z = f2bf(v.z - bf2f(h.z)); g.z = f2h(bf2f(h.z) + bf2f(l.z));
    h.w = f2bf(v.w); l.w = f2bf(v.w - bf2f(h.w)); g.w = f2h(bf2f(h.w) + bf2f(l.w));
    *(ushort4*)(ch + (size_t)(b0 + bl_) * 1024 + d0 + dl) = h;
    *(ushort4*)(cl + (size_t)(b0 + bl_) * 1024 + d0 + dl) = l;
    *(ushort4*)(cg + (size_t)(b0 + bl_) * 1024 + d0 + dl) = g;
    th[bl_][dl] = h.x; th[bl_][dl + 1] = h.y; th[bl_][dl + 2] = h.z; th[bl_][dl + 3] = h.w;
    tl[bl_][dl] = l.x; tl[bl_][dl + 1] = l.y; tl[bl_][dl + 2] = l.z; tl[bl_][dl + 3] = l.w;
  }
  __syncthreads();
#pragma unroll
  for (int i = 0; i < 4; ++i) {
    int flat = t + i * 256;
    int dl = flat >> 4;
    int bl_ = (flat & 15) << 2;
    ushort4 h = make_ushort4(th[bl_][dl], th[bl_ + 1][dl], th[bl_ + 2][dl], th[bl_ + 3][dl]);
    ushort4 l = make_ushort4(tl[bl_][dl], tl[bl_ + 1][dl], tl[bl_ + 2][dl], tl[bl_ + 3][dl]);
    ushort4 g;
    g.x = f2h(bf2f(h.x) + bf2f(l.x));
    g.y = f2h(bf2f(h.y) + bf2f(l.y));
    g.z = f2h(bf2f(h.z) + bf2f(l.z));
    g.w = f2h(bf2f(h.w) + bf2f(l.w));
    *(ushort4*)(cTh + (size_t)(d0 + dl) * 8192 + b0 + bl_) = h;
    *(ushort4*)(cTl + (size_t)(d0 + dl) * 8192 + b0 + bl_) = l;
    *(ushort4*)(cTg + (size_t)(d0 + dl) * 8192 + b0 + bl_) = g;
  }
}

// f32 -> hi/lo bf16
__global__ __launch_bounds__(256) void split_f32(const float* __restrict__ in,
                                                 unsigned short* __restrict__ hi,
                                                 unsigned short* __restrict__ lo) {
  const size_t i = (size_t)(blockIdx.x * blockDim.x + threadIdx.x) * 4;
  float4 v = *(const float4*)(in + i);
  ushort4 h, l;
  h.x = f2bf(v.x); l.x = f2bf(v.x - bf2f(h.x));
  h.y = f2bf(v.y); l.y = f2bf(v.y - bf2f(h.y));
  h.z = f2bf(v.z); l.z = f2bf(v.z - bf2f(h.z));
  h.w = f2bf(v.w); l.w = f2bf(v.w - bf2f(h.w));
  *(ushort4*)(hi + i) = h;
  *(ushort4*)(lo + i) = l;
}

// ---------------------------------------------------------------------------
// Fused row-softmax + transpose (split-K partial input), iter-1 path only.
// ---------------------------------------------------------------------------
template <bool HILO>
__global__ __launch_bounds__(512) void rowsoftmax_T(
    const float* __restrict__ SP0, const float* __restrict__ SP1,
    unsigned short* __restrict__ rTh, unsigned short* __restrict__ rTl) {
  __shared__ __align__(16) unsigned short th[32 * 520];
  __shared__ __align__(16) unsigned short tl[HILO ? 32 * 520 : 8];
  const int t = threadIdx.x;
  const int lane = t & 63, w = t >> 6;
  const int b0 = blockIdx.x * 32;
#pragma unroll
  for (int k = 0; k < 4; ++k) {
    const int bl = w * 4 + k;
    const int row = b0 + bl;
    const size_t off = (size_t)row * 512 + lane * 8;
    float4 v0 = *(const float4*)(SP0 + off);
    float4 v1 = *(const float4*)(SP0 + off + 4);
    float4 u0 = *(const float4*)(SP1 + off);
    float4 u1 = *(const float4*)(SP1 + off + 4);
    float e[8];
    e[0] = v0.x + u0.x; e[1] = v0.y + u0.y; e[2] = v0.z + u0.z; e[3] = v0.w + u0.w;
    e[4] = v1.x + u1.x; e[5] = v1.y + u1.y; e[6] = v1.z + u1.z; e[7] = v1.w + u1.w;
    float m = fmaxf(fmaxf(fmaxf(e[0], e[1]), fmaxf(e[2], e[3])),
                    fmaxf(fmaxf(e[4], e[5]), fmaxf(e[6], e[7])));
    for (int o = 32; o; o >>= 1) m = fmaxf(m, __shfl_xor(m, o));
    float s = 0.f;
#pragma unroll
    for (int i = 0; i < 8; ++i) { e[i] = __expf(e[i] - m); s += e[i]; }
    for (int o = 32; o; o >>= 1) s += __shfl_xor(s, o);
    const float inv = 1.f / s;
    unsigned short ph[8], pl[8];
#pragma unroll
    for (int i = 0; i < 8; ++i) {
      const float r = e[i] * inv;
      if constexpr (HILO) {
        ph[i] = f2bf(r);
        pl[i] = f2bf(r - bf2f(ph[i]));
      } else {
        ph[i] = f2h(r);
      }
    }
    *(v8s*)&th[bl * 520 + lane * 8] = *(v8s*)ph;
    if constexpr (HILO) *(v8s*)&tl[bl * 520 + lane * 8] = *(v8s*)pl;
  }
  __syncthreads();
  const int c = t;
  unsigned short uh[32];
#pragma unroll
  for (int b = 0; b < 32; ++b) uh[b] = th[b * 520 + c];
#pragma unroll
  for (int q = 0; q < 4; ++q)
    *(v8s*)(rTh + (size_t)c * 8192 + b0 + q * 8) = *(v8s*)&uh[q * 8];
  if constexpr (HILO) {
    unsigned short ul[32];
#pragma unroll
    for (int b = 0; b < 32; ++b) ul[b] = tl[b * 520 + c];
#pragma unroll
    for (int q = 0; q < 4; ++q)
      *(v8s*)(rTl + (size_t)c * 8192 + b0 + q * 8) = *(v8s*)&ul[q * 8];
  }
}

// Sum 16 split-K partials [512][1024], L2-normalize rows (+1e-6),
// emit p fp16 [512][1024] + pT fp16 [1024][512].
__global__ __launch_bounds__(256) void reduce_normalize(const float* __restrict__ Pp,
                                                        unsigned short* __restrict__ pg,
                                                        unsigned short* __restrict__ pTg) {
  __shared__ float red[4];
  const int c = blockIdx.x, t = threadIdx.x;
  float ax = 0.f, ay = 0.f, az = 0.f, aw = 0.f;
#pragma unroll
  for (int s = 0; s < 16; ++s) {
    const float4 v = *(const float4*)(Pp + ((size_t)s * 512 + c) * 1024 + t * 4);
    ax += v.x; ay += v.y; az += v.z; aw += v.w;
  }
  float ss = ax * ax + ay * ay + az * az + aw * aw;
  for (int off = 32; off; off >>= 1) ss += __shfl_xor(ss, off);
  const int w = t >> 6, lane = t & 63;
  if (!lane) red[w] = ss;
  __syncthreads();
  const float tot = red[0] + red[1] + red[2] + red[3];
  const float scale = 1.f / (sqrtf(tot) + 1e-6f);
  ax *= scale; ay *= scale; az *= scale; aw *= scale;
  *(ushort4*)(pg + (size_t)c * 1024 + t * 4) =
      make_ushort4(f2h(ax), f2h(ay), f2h(az), f2h(aw));
  pTg[(size_t)(t * 4 + 0) * 512 + c] = f2h(ax);
  pTg[(size_t)(t * 4 + 1) * 512 + c] = f2h(ay);
  pTg[(size_t)(t * 4 + 2) * 512 + c] = f2h(az);
  pTg[(size_t)(t * 4 + 3) * 512 + c] = f2h(aw);
}

extern "C" void kernel_launch(void* const* d_in, const int* in_sizes, int n_in,
                              void* d_out, int out_size, void* d_ws, size_t ws_size,
                              hipStream_t stream) {
  const float* cls = (const float*)d_in[0];     // [8192,1024]
  const float* proto = (const float*)d_in[1];   // [512,1024]
  float* out_r = (float*)d_out;                 // [8192,512]
  float* out_z = out_r + (size_t)8192 * 512;    // [8192,1024]

  char* w = (char*)d_ws;
  unsigned short* cls_h = (unsigned short*)w; w += (size_t)8192 * 1024 * 2;  // 16 MB
  unsigned short* cls_l = (unsigned short*)w; w += (size_t)8192 * 1024 * 2;  // 16 MB
  unsigned short* clsT_h = (unsigned short*)w; w += (size_t)1024 * 8192 * 2; // 16 MB
  unsigned short* clsT_l = (unsigned short*)w; w += (size_t)1024 * 8192 * 2; // 16 MB
  unsigned short* cls_g = (unsigned short*)w; w += (size_t)8192 * 1024 * 2;  // 16 MB (fp16)
  unsigned short* clsT_g = (unsigned short*)w; w += (size_t)1024 * 8192 * 2; // 16 MB (fp16)
  unsigned short* p_h = (unsigned short*)w; w += (size_t)512 * 1024 * 2;     //  1 MB
  unsigned short* p_l = (unsigned short*)w; w += (size_t)512 * 1024 * 2;     //  1 MB
  unsigned short* p_g = (unsigned short*)w; w += (size_t)512 * 1024 * 2;     //  1 MB (fp16)
  unsigned short* pT_g = (unsigned short*)w; w += (size_t)1024 * 512 * 2;    //  1 MB (fp16)
  unsigned short* rT_h = (unsigned short*)w; w += (size_t)512 * 8192 * 2;    //  8 MB (also fp16 r)
  unsigned short* rT_l = (unsigned short*)w; w += (size_t)512 * 8192 * 2;    //  8 MB
  float* SP = (float*)w;  // 32 MB: [2][8192][512] / [16][512][1024]
  float* SP1 = SP + (size_t)8192 * 512;

  // One-pass cast: bf16 hi/lo (row + T) for iter-1 and fp16 (row + T).
  cast_split_transpose_cls<<<dim3(16, 128), 256, 0, stream>>>(
      cls, cls_h, cls_l, clsT_h, clsT_l, cls_g, clsT_g);
  split_f32<<<512, 256, 0, stream>>>(proto, p_h, p_l);

  // EM iteration 1: compensated bf16.
  gemm_bt3<<<dim3(4, 64, 2), 256, 0, stream>>>(cls_h, cls_l, p_h, p_l, SP,
                                               512, 1024, 1024, 512,
                                               (size_t)8192 * 512);
  rowsoftmax_T<true><<<256, 512, 0, stream>>>(SP, SP1, rT_h, rT_l);
  gemm_bt3<<<dim3(8, 4, 16), 256, 0, stream>>>(rT_h, rT_l, clsT_h, clsT_l, SP,
                                               1024, 8192, 8192, 512,
                                               (size_t)512 * 1024);
  reduce_normalize<<<512, 256, 0, stream>>>(SP, p_g, pT_g);

  // EM iterations 2-5: fused S+softmax (no SP round-trip), P-GEMM, normalize.
  for (int it = 0; it < 4; ++it) {
    s_softmax_fused<false><<<256, 256, 0, stream>>>(cls_g, p_g, rT_h, nullptr, nullptr);
    gemm_bt<false, true><<<dim3(8, 4, 16), 256, 0, stream>>>(rT_h, clsT_g, SP, nullptr,
                                                             1024, 8192, 8192, 512,
                                                             (size_t)512 * 1024);
    reduce_normalize<<<512, 256, 0, stream>>>(SP, p_g, pT_g);
  }

  // Final stage: fused S+softmax writes r f32 + r fp16; z = r @ p + cls.
  s_softmax_fused<true><<<256, 256, 0, stream>>>(cls_g, p_g, nullptr, out_r, rT_h);
  gemm_bt<true, true><<<dim3(8, 64, 1), 256, 0, stream>>>(rT_h, pT_g, out_z, cls,
                                                          1024, 512, 512, 512, 0);
}

// Round 8
// 450.687 us; speedup vs baseline: 1.0455x; 1.0455x over previous
//
#include <hip/hip_runtime.h>

typedef short v8s __attribute__((ext_vector_type(8)));
typedef _Float16 v8h __attribute__((ext_vector_type(8)));
typedef float v4f __attribute__((ext_vector_type(4)));

typedef __attribute__((address_space(1))) const void* as1_void_cp;
typedef __attribute__((address_space(3))) void* as3_void_p;

__device__ __forceinline__ unsigned short f2bf(float x) {
  union { float f; unsigned int u; } v; v.f = x;
  unsigned int r = v.u + 0x7fffu + ((v.u >> 16) & 1u);
  return (unsigned short)(r >> 16);
}
__device__ __forceinline__ float bf2f(unsigned short h) {
  union { unsigned int u; float f; } v; v.u = ((unsigned int)h) << 16;
  return v.f;
}
__device__ __forceinline__ unsigned short f2h(float x) {
  _Float16 h = (_Float16)x;  // RTE
  return __builtin_bit_cast(unsigned short, h);
}

// XCD-aware bijective block swizzle (T1/m204): each XCD gets a CONTIGUOUS
// chunk of logical tiles -> shared A/B panels fetched once per XCD-L2.
struct B3 { int x, y, z; };
__device__ __forceinline__ B3 xcd_swizzle() {
  const int gx = gridDim.x, gy = gridDim.y;
  const int nwg = gx * gy * gridDim.z;
  int flat = blockIdx.x + gx * (blockIdx.y + gy * blockIdx.z);
  if ((nwg & 7) == 0) flat = (flat & 7) * (nwg >> 3) + (flat >> 3);
  B3 b;
  b.x = flat % gx;
  b.y = (flat / gx) % gy;
  b.z = flat / (gx * gy);
  return b;
}

// ---------------------------------------------------------------------------
// Plain GEMM (bf16 or fp16 per F16): C[MxN](f32) = A[MxK] @ B[NxK]^T.
// 128x128 tile, BK=64. Double-buffered LDS, counted vmcnt, XCD swizzle.
// ---------------------------------------------------------------------------
template <bool ADD, bool F16>
__global__ __launch_bounds__(256) void gemm_bt(
    const unsigned short* __restrict__ A, const unsigned short* __restrict__ B,
    float* __restrict__ C, const float* __restrict__ Cadd,
    int N, int lda, int ldb, int klen, size_t csplit) {
  __shared__ __align__(16) unsigned short As[2][128 * 64];
  __shared__ __align__(16) unsigned short Bs[2][128 * 64];
  const int tid = threadIdx.x;
  const B3 bid = xcd_swizzle();
  const int bn = bid.x * 128, bm = bid.y * 128;
  const int k0 = bid.z * klen;
  float* Cp = C + (size_t)bid.z * csplit;

  const unsigned short* ag0 = A + (size_t)(bm + (tid >> 2)) * lda + ((tid & 3) << 3) + k0;
  const unsigned short* ag1 = ag0 + (size_t)64 * lda;
  const unsigned short* bg0 = B + (size_t)(bn + (tid >> 2)) * ldb + ((tid & 3) << 3) + k0;
  const unsigned short* bg1 = bg0 + (size_t)64 * ldb;

  const int lane = tid & 63;
  const int q = lane >> 4, m15 = lane & 15;
  const int w = tid >> 6;
  const int wr = (w >> 1) * 64, wc = (w & 1) * 64;

  v4f acc[4][4];
#pragma unroll
  for (int i = 0; i < 4; ++i)
#pragma unroll
    for (int j = 0; j < 4; ++j) acc[i][j] = 0.f;

  auto stage = [&](int kk, int b) {
    unsigned short* al = As[b] + tid * 8;
    unsigned short* bl = Bs[b] + tid * 8;
    __builtin_amdgcn_global_load_lds((as1_void_cp)(ag0 + kk), (as3_void_p)al, 16, 0, 0);
    __builtin_amdgcn_global_load_lds((as1_void_cp)(ag1 + kk), (as3_void_p)(al + 2048), 16, 0, 0);
    __builtin_amdgcn_global_load_lds((as1_void_cp)(ag0 + kk + 32), (as3_void_p)(al + 4096), 16, 0, 0);
    __builtin_amdgcn_global_load_lds((as1_void_cp)(ag1 + kk + 32), (as3_void_p)(al + 6144), 16, 0, 0);
    __builtin_amdgcn_global_load_lds((as1_void_cp)(bg0 + kk), (as3_void_p)bl, 16, 0, 0);
    __builtin_amdgcn_global_load_lds((as1_void_cp)(bg1 + kk), (as3_void_p)(bl + 2048), 16, 0, 0);
    __builtin_amdgcn_global_load_lds((as1_void_cp)(bg0 + kk + 32), (as3_void_p)(bl + 4096), 16, 0, 0);
    __builtin_amdgcn_global_load_lds((as1_void_cp)(bg1 + kk + 32), (as3_void_p)(bl + 6144), 16, 0, 0);
  };

  const int nt = klen >> 6;
  stage(0, 0);
  if (nt > 1) stage(64, 1);
  for (int t = 0; t < nt; ++t) {
    if (t + 1 < nt)
      asm volatile("s_waitcnt vmcnt(8)" ::: "memory");
    else
      asm volatile("s_waitcnt vmcnt(0)" ::: "memory");
    __builtin_amdgcn_s_barrier();
    const unsigned short* Ab = As[t & 1];
    const unsigned short* Bb = Bs[t & 1];
#pragma unroll
    for (int h = 0; h < 2; ++h) {
      v8s af[4], bf[4];
#pragma unroll
      for (int i = 0; i < 4; ++i)
        af[i] = *(const v8s*)(Ab + h * 4096 + (wr + i * 16 + m15) * 32 + q * 8);
#pragma unroll
      for (int j = 0; j < 4; ++j)
        bf[j] = *(const v8s*)(Bb + h * 4096 + (wc + j * 16 + m15) * 32 + q * 8);
#pragma unroll
      for (int i = 0; i < 4; ++i)
#pragma unroll
        for (int j = 0; j < 4; ++j) {
          if constexpr (F16)
            acc[i][j] = __builtin_amdgcn_mfma_f32_16x16x32_f16(
                __builtin_bit_cast(v8h, af[i]), __builtin_bit_cast(v8h, bf[j]), acc[i][j], 0, 0, 0);
          else
            acc[i][j] = __builtin_amdgcn_mfma_f32_16x16x32_bf16(af[i], bf[j], acc[i][j], 0, 0, 0);
        }
    }
    if (t + 2 < nt) {
      __builtin_amdgcn_s_barrier();
      stage((t + 2) << 6, t & 1);
    }
  }

#pragma unroll
  for (int i = 0; i < 4; ++i) {
#pragma unroll
    for (int j = 0; j < 4; ++j) {
      const int col = bn + wc + j * 16 + m15;
#pragma unroll
      for (int rr = 0; rr < 4; ++rr) {
        const int row = bm + wr + i * 16 + q * 4 + rr;
        const size_t idx = (size_t)row * N + col;
        float v = acc[i][j][rr];
        if (ADD) v += Cadd[idx];
        Cp[idx] = v;
      }
    }
  }
}

// ---------------------------------------------------------------------------
// Split-bf16 (compensated) GEMM: C = (Ah+Al)@(Bh+Bl)^T dropping Al*Bl.
// EM iteration 1 only. BK=32, dbuf + counted vmcnt + XCD swizzle.
// ---------------------------------------------------------------------------
__global__ __launch_bounds__(256) void gemm_bt3(
    const unsigned short* __restrict__ Ah, const unsigned short* __restrict__ Al,
    const unsigned short* __restrict__ Bh, const unsigned short* __restrict__ Bl,
    float* __restrict__ C, int N, int lda, int ldb, int klen, size_t csplit) {
  __shared__ __align__(16) unsigned short Ash[2][128 * 32];
  __shared__ __align__(16) unsigned short Asl[2][128 * 32];
  __shared__ __align__(16) unsigned short Bsh[2][128 * 32];
  __shared__ __align__(16) unsigned short Bsl[2][128 * 32];
  const int tid = threadIdx.x;
  const B3 bid = xcd_swizzle();
  const int bn = bid.x * 128, bm = bid.y * 128;
  const int k0 = bid.z * klen;
  float* Cp = C + (size_t)bid.z * csplit;

  const size_t aoff = (size_t)(bm + (tid >> 2)) * lda + ((tid & 3) << 3) + k0;
  const size_t boff = (size_t)(bn + (tid >> 2)) * ldb + ((tid & 3) << 3) + k0;
  const unsigned short* agh0 = Ah + aoff;
  const unsigned short* agh1 = agh0 + (size_t)64 * lda;
  const unsigned short* agl0 = Al + aoff;
  const unsigned short* agl1 = agl0 + (size_t)64 * lda;
  const unsigned short* bgh0 = Bh + boff;
  const unsigned short* bgh1 = bgh0 + (size_t)64 * ldb;
  const unsigned short* bgl0 = Bl + boff;
  const unsigned short* bgl1 = bgl0 + (size_t)64 * ldb;

  const int lane = tid & 63;
  const int q = lane >> 4, m15 = lane & 15;
  const int w = tid >> 6;
  const int wr = (w >> 1) * 64, wc = (w & 1) * 64;

  v4f acc[4][4];
#pragma unroll
  for (int i = 0; i < 4; ++i)
#pragma unroll
    for (int j = 0; j < 4; ++j) acc[i][j] = 0.f;

  auto stage = [&](int kk, int b) {
    __builtin_amdgcn_global_load_lds((as1_void_cp)(agh0 + kk), (as3_void_p)(Ash[b] + tid * 8), 16, 0, 0);
    __builtin_amdgcn_global_load_lds((as1_void_cp)(agh1 + kk), (as3_void_p)(Ash[b] + 2048 + tid * 8), 16, 0, 0);
    __builtin_amdgcn_global_load_lds((as1_void_cp)(agl0 + kk), (as3_void_p)(Asl[b] + tid * 8), 16, 0, 0);
    __builtin_amdgcn_global_load_lds((as1_void_cp)(agl1 + kk), (as3_void_p)(Asl[b] + 2048 + tid * 8), 16, 0, 0);
    __builtin_amdgcn_global_load_lds((as1_void_cp)(bgh0 + kk), (as3_void_p)(Bsh[b] + tid * 8), 16, 0, 0);
    __builtin_amdgcn_global_load_lds((as1_void_cp)(bgh1 + kk), (as3_void_p)(Bsh[b] + 2048 + tid * 8), 16, 0, 0);
    __builtin_amdgcn_global_load_lds((as1_void_cp)(bgl0 + kk), (as3_void_p)(Bsl[b] + tid * 8), 16, 0, 0);
    __builtin_amdgcn_global_load_lds((as1_void_cp)(bgl1 + kk), (as3_void_p)(Bsl[b] + 2048 + tid * 8), 16, 0, 0);
  };

  const int nt = klen >> 5;
  stage(0, 0);
  if (nt > 1) stage(32, 1);
  for (int t = 0; t < nt; ++t) {
    if (t + 1 < nt)
      asm volatile("s_waitcnt vmcnt(8)" ::: "memory");
    else
      asm volatile("s_waitcnt vmcnt(0)" ::: "memory");
    __builtin_amdgcn_s_barrier();
    const int b = t & 1;
    v8s afh[4], afl[4], bfh[4], bfl[4];
#pragma unroll
    for (int i = 0; i < 4; ++i) {
      const int ro = (wr + i * 16 + m15) * 32 + q * 8;
      afh[i] = *(const v8s*)(Ash[b] + ro);
      afl[i] = *(const v8s*)(Asl[b] + ro);
    }
#pragma unroll
    for (int j = 0; j < 4; ++j) {
      const int ro = (wc + j * 16 + m15) * 32 + q * 8;
      bfh[j] = *(const v8s*)(Bsh[b] + ro);
      bfl[j] = *(const v8s*)(Bsl[b] + ro);
    }
#pragma unroll
    for (int i = 0; i < 4; ++i)
#pragma unroll
      for (int j = 0; j < 4; ++j) {
        acc[i][j] = __builtin_amdgcn_mfma_f32_16x16x32_bf16(afh[i], bfh[j], acc[i][j], 0, 0, 0);
        acc[i][j] = __builtin_amdgcn_mfma_f32_16x16x32_bf16(afh[i], bfl[j], acc[i][j], 0, 0, 0);
        acc[i][j] = __builtin_amdgcn_mfma_f32_16x16x32_bf16(afl[i], bfh[j], acc[i][j], 0, 0, 0);
      }
    if (t + 2 < nt) {
      __builtin_amdgcn_s_barrier();
      stage((t + 2) << 5, b);
    }
  }

#pragma unroll
  for (int i = 0; i < 4; ++i) {
#pragma unroll
    for (int j = 0; j < 4; ++j) {
      const int col = bn + wc + j * 16 + m15;
#pragma unroll
      for (int rr = 0; rr < 4; ++rr) {
        const int row = bm + wr + i * 16 + q * 4 + rr;
        Cp[(size_t)row * N + col] = acc[i][j][rr];
      }
    }
  }
}

// cls f32 [8192][1024] -> hi/lo bf16 (row + transposed) AND fp16 (row +
// transposed), one pass. fp16 = f2h(hi+lo).
__global__ __launch_bounds__(256) void cast_split_transpose_cls(
    const float* __restrict__ cls,
    unsigned short* __restrict__ ch, unsigned short* __restrict__ cl,
    unsigned short* __restrict__ cTh, unsigned short* __restrict__ cTl,
    unsigned short* __restrict__ cg, unsigned short* __restrict__ cTg) {
  __shared__ unsigned short th[64][72];
  __shared__ unsigned short tl[64][72];
  const int d0 = blockIdx.x * 64, b0 = blockIdx.y * 64;
  const int t = threadIdx.x;
#pragma unroll
  for (int i = 0; i < 4; ++i) {
    int flat = t + i * 256;
    int bl_ = flat >> 4;
    int dl = (flat & 15) << 2;
    float4 v = *(const float4*)(cls + (size_t)(b0 + bl_) * 1024 + d0 + dl);
    ushort4 h, l, g;
    h.x = f2bf(v.x); l.x = f2bf(v.x - bf2f(h.x)); g.x = f2h(bf2f(h.x) + bf2f(l.x));
    h.y = f2bf(v.y); l.y = f2bf(v.y - bf2f(h.y)); g.y = f2h(bf2f(h.y) + bf2f(l.y));
    h.z = f2bf(v.z); l.z = f2bf(v.z - bf2f(h.z)); g.z = f2h(bf2f(h.z) + bf2f(l.z));
    h.w = f2bf(v.w); l.w = f2bf(v.w - bf2f(h.w)); g.w = f2h(bf2f(h.w) + bf2f(l.w));
    *(ushort4*)(ch + (size_t)(b0 + bl_) * 1024 + d0 + dl) = h;
    *(ushort4*)(cl + (size_t)(b0 + bl_) * 1024 + d0 + dl) = l;
    *(ushort4*)(cg + (size_t)(b0 + bl_) * 1024 + d0 + dl) = g;
    th[bl_][dl] = h.x; th[bl_][dl + 1] = h.y; th[bl_][dl + 2] = h.z; th[bl_][dl + 3] = h.w;
    tl[bl_][dl] = l.x; tl[bl_][dl + 1] = l.y; tl[bl_][dl + 2] = l.z; tl[bl_][dl + 3] = l.w;
  }
  __syncthreads();
#pragma unroll
  for (int i = 0; i < 4; ++i) {
    int flat = t + i * 256;
    int dl = flat >> 4;
    int bl_ = (flat & 15) << 2;
    ushort4 h = make_ushort4(th[bl_][dl], th[bl_ + 1][dl], th[bl_ + 2][dl], th[bl_ + 3][dl]);
    ushort4 l = make_ushort4(tl[bl_][dl], tl[bl_ + 1][dl], tl[bl_ + 2][dl], tl[bl_ + 3][dl]);
    ushort4 g;
    g.x = f2h(bf2f(h.x) + bf2f(l.x));
    g.y = f2h(bf2f(h.y) + bf2f(l.y));
    g.z = f2h(bf2f(h.z) + bf2f(l.z));
    g.w = f2h(bf2f(h.w) + bf2f(l.w));
    *(ushort4*)(cTh + (size_t)(d0 + dl) * 8192 + b0 + bl_) = h;
    *(ushort4*)(cTl + (size_t)(d0 + dl) * 8192 + b0 + bl_) = l;
    *(ushort4*)(cTg + (size_t)(d0 + dl) * 8192 + b0 + bl_) = g;
  }
}

// f32 -> hi/lo bf16
__global__ __launch_bounds__(256) void split_f32(const float* __restrict__ in,
                                                 unsigned short* __restrict__ hi,
                                                 unsigned short* __restrict__ lo) {
  const size_t i = (size_t)(blockIdx.x * blockDim.x + threadIdx.x) * 4;
  float4 v = *(const float4*)(in + i);
  ushort4 h, l;
  h.x = f2bf(v.x); l.x = f2bf(v.x - bf2f(h.x));
  h.y = f2bf(v.y); l.y = f2bf(v.y - bf2f(h.y));
  h.z = f2bf(v.z); l.z = f2bf(v.z - bf2f(h.z));
  h.w = f2bf(v.w); l.w = f2bf(v.w - bf2f(h.w));
  *(ushort4*)(hi + i) = h;
  *(ushort4*)(lo + i) = l;
}

// ---------------------------------------------------------------------------
// Fused row-softmax + transpose: S = SP0+SP1 ([b=8192][c=512] f32, split-K
// partials), row softmax over c, write rT ([c=512][b=8192]).
// HILO: bf16 hi/lo pair (iter 1); else single fp16.
// ---------------------------------------------------------------------------
template <bool HILO>
__global__ __launch_bounds__(512) void rowsoftmax_T(
    const float* __restrict__ SP0, const float* __restrict__ SP1,
    unsigned short* __restrict__ rTh, unsigned short* __restrict__ rTl) {
  __shared__ __align__(16) unsigned short th[32 * 520];
  __shared__ __align__(16) unsigned short tl[HILO ? 32 * 520 : 8];
  const int t = threadIdx.x;
  const int lane = t & 63, w = t >> 6;
  const int b0 = blockIdx.x * 32;
#pragma unroll
  for (int k = 0; k < 4; ++k) {
    const int bl = w * 4 + k;
    const int row = b0 + bl;
    const size_t off = (size_t)row * 512 + lane * 8;
    float4 v0 = *(const float4*)(SP0 + off);
    float4 v1 = *(const float4*)(SP0 + off + 4);
    float4 u0 = *(const float4*)(SP1 + off);
    float4 u1 = *(const float4*)(SP1 + off + 4);
    float e[8];
    e[0] = v0.x + u0.x; e[1] = v0.y + u0.y; e[2] = v0.z + u0.z; e[3] = v0.w + u0.w;
    e[4] = v1.x + u1.x; e[5] = v1.y + u1.y; e[6] = v1.z + u1.z; e[7] = v1.w + u1.w;
    float m = fmaxf(fmaxf(fmaxf(e[0], e[1]), fmaxf(e[2], e[3])),
                    fmaxf(fmaxf(e[4], e[5]), fmaxf(e[6], e[7])));
    for (int o = 32; o; o >>= 1) m = fmaxf(m, __shfl_xor(m, o));
    float s = 0.f;
#pragma unroll
    for (int i = 0; i < 8; ++i) { e[i] = __expf(e[i] - m); s += e[i]; }
    for (int o = 32; o; o >>= 1) s += __shfl_xor(s, o);
    const float inv = 1.f / s;
    unsigned short ph[8], pl[8];
#pragma unroll
    for (int i = 0; i < 8; ++i) {
      const float r = e[i] * inv;
      if constexpr (HILO) {
        ph[i] = f2bf(r);
        pl[i] = f2bf(r - bf2f(ph[i]));
      } else {
        ph[i] = f2h(r);
      }
    }
    *(v8s*)&th[bl * 520 + lane * 8] = *(v8s*)ph;
    if constexpr (HILO) *(v8s*)&tl[bl * 520 + lane * 8] = *(v8s*)pl;
  }
  __syncthreads();
  // write-out: thread t owns c-row t; 32 b values -> one 64B contiguous chunk
  const int c = t;
  unsigned short uh[32];
#pragma unroll
  for (int b = 0; b < 32; ++b) uh[b] = th[b * 520 + c];
#pragma unroll
  for (int q = 0; q < 4; ++q)
    *(v8s*)(rTh + (size_t)c * 8192 + b0 + q * 8) = *(v8s*)&uh[q * 8];
  if constexpr (HILO) {
    unsigned short ul[32];
#pragma unroll
    for (int b = 0; b < 32; ++b) ul[b] = tl[b * 520 + c];
#pragma unroll
    for (int q = 0; q < 4; ++q)
      *(v8s*)(rTl + (size_t)c * 8192 + b0 + q * 8) = *(v8s*)&ul[q * 8];
  }
}

// Final: row softmax of SP0+SP1 [8192][512] -> r f32 (d_out) + r fp16 row-major.
__global__ __launch_bounds__(256) void softmax_rows(const float* __restrict__ SP0,
                                                    const float* __restrict__ SP1,
                                                    float* __restrict__ r_out,
                                                    unsigned short* __restrict__ r_g) {
  const int w = threadIdx.x >> 6, lane = threadIdx.x & 63;
  const int row = blockIdx.x * 4 + w;
  const size_t off = (size_t)row * 512 + lane * 8;
  float4 v0 = *(const float4*)(SP0 + off);
  float4 v1 = *(const float4*)(SP0 + off + 4);
  float4 u0 = *(const float4*)(SP1 + off);
  float4 u1 = *(const float4*)(SP1 + off + 4);
  v0.x += u0.x; v0.y += u0.y; v0.z += u0.z; v0.w += u0.w;
  v1.x += u1.x; v1.y += u1.y; v1.z += u1.z; v1.w += u1.w;
  float m = fmaxf(fmaxf(fmaxf(v0.x, v0.y), fmaxf(v0.z, v0.w)),
                  fmaxf(fmaxf(v1.x, v1.y), fmaxf(v1.z, v1.w)));
  for (int off2 = 32; off2; off2 >>= 1) m = fmaxf(m, __shfl_xor(m, off2));
  float e0 = __expf(v0.x - m), e1 = __expf(v0.y - m), e2 = __expf(v0.z - m), e3 = __expf(v0.w - m);
  float e4 = __expf(v1.x - m), e5 = __expf(v1.y - m), e6 = __expf(v1.z - m), e7 = __expf(v1.w - m);
  float s = e0 + e1 + e2 + e3 + e4 + e5 + e6 + e7;
  for (int off2 = 32; off2; off2 >>= 1) s += __shfl_xor(s, off2);
  const float inv = 1.f / s;
  e0 *= inv; e1 *= inv; e2 *= inv; e3 *= inv; e4 *= inv; e5 *= inv; e6 *= inv; e7 *= inv;
  float* rp = r_out + off;
  *(float4*)rp = make_float4(e0, e1, e2, e3);
  *(float4*)(rp + 4) = make_float4(e4, e5, e6, e7);
  unsigned short* bp = r_g + off;
  *(ushort4*)bp = make_ushort4(f2h(e0), f2h(e1), f2h(e2), f2h(e3));
  *(ushort4*)(bp + 4) = make_ushort4(f2h(e4), f2h(e5), f2h(e6), f2h(e7));
}

// Sum 16 split-K partials [512][1024], L2-normalize rows (+1e-6),
// emit p fp16 [512][1024] + pT fp16 [1024][512].
__global__ __launch_bounds__(256) void reduce_normalize(const float* __restrict__ Pp,
                                                        unsigned short* __restrict__ pg,
                                                        unsigned short* __restrict__ pTg) {
  __shared__ float red[4];
  const int c = blockIdx.x, t = threadIdx.x;
  float ax = 0.f, ay = 0.f, az = 0.f, aw = 0.f;
#pragma unroll
  for (int s = 0; s < 16; ++s) {
    const float4 v = *(const float4*)(Pp + ((size_t)s * 512 + c) * 1024 + t * 4);
    ax += v.x; ay += v.y; az += v.z; aw += v.w;
  }
  float ss = ax * ax + ay * ay + az * az + aw * aw;
  for (int off = 32; off; off >>= 1) ss += __shfl_xor(ss, off);
  const int w = t >> 6, lane = t & 63;
  if (!lane) red[w] = ss;
  __syncthreads();
  const float tot = red[0] + red[1] + red[2] + red[3];
  const float scale = 1.f / (sqrtf(tot) + 1e-6f);
  ax *= scale; ay *= scale; az *= scale; aw *= scale;
  *(ushort4*)(pg + (size_t)c * 1024 + t * 4) =
      make_ushort4(f2h(ax), f2h(ay), f2h(az), f2h(aw));
  pTg[(size_t)(t * 4 + 0) * 512 + c] = f2h(ax);
  pTg[(size_t)(t * 4 + 1) * 512 + c] = f2h(ay);
  pTg[(size_t)(t * 4 + 2) * 512 + c] = f2h(az);
  pTg[(size_t)(t * 4 + 3) * 512 + c] = f2h(aw);
}

extern "C" void kernel_launch(void* const* d_in, const int* in_sizes, int n_in,
                              void* d_out, int out_size, void* d_ws, size_t ws_size,
                              hipStream_t stream) {
  const float* cls = (const float*)d_in[0];     // [8192,1024]
  const float* proto = (const float*)d_in[1];   // [512,1024]
  float* out_r = (float*)d_out;                 // [8192,512]
  float* out_z = out_r + (size_t)8192 * 512;    // [8192,1024]

  char* w = (char*)d_ws;
  unsigned short* cls_h = (unsigned short*)w; w += (size_t)8192 * 1024 * 2;  // 16 MB
  unsigned short* cls_l = (unsigned short*)w; w += (size_t)8192 * 1024 * 2;  // 16 MB
  unsigned short* clsT_h = (unsigned short*)w; w += (size_t)1024 * 8192 * 2; // 16 MB
  unsigned short* clsT_l = (unsigned short*)w; w += (size_t)1024 * 8192 * 2; // 16 MB
  unsigned short* cls_g = (unsigned short*)w; w += (size_t)8192 * 1024 * 2;  // 16 MB (fp16)
  unsigned short* clsT_g = (unsigned short*)w; w += (size_t)1024 * 8192 * 2; // 16 MB (fp16)
  unsigned short* p_h = (unsigned short*)w; w += (size_t)512 * 1024 * 2;     //  1 MB
  unsigned short* p_l = (unsigned short*)w; w += (size_t)512 * 1024 * 2;     //  1 MB
  unsigned short* p_g = (unsigned short*)w; w += (size_t)512 * 1024 * 2;     //  1 MB (fp16)
  unsigned short* pT_g = (unsigned short*)w; w += (size_t)1024 * 512 * 2;    //  1 MB (fp16)
  unsigned short* rT_h = (unsigned short*)w; w += (size_t)512 * 8192 * 2;    //  8 MB (also fp16 r)
  unsigned short* rT_l = (unsigned short*)w; w += (size_t)512 * 8192 * 2;    //  8 MB
  float* SP = (float*)w;  // 32 MB: [2][8192][512] / [16][512][1024]
  float* SP1 = SP + (size_t)8192 * 512;

  // One-pass cast: bf16 hi/lo (row + T) for iter-1 and fp16 (row + T).
  cast_split_transpose_cls<<<dim3(16, 128), 256, 0, stream>>>(
      cls, cls_h, cls_l, clsT_h, clsT_l, cls_g, clsT_g);
  split_f32<<<512, 256, 0, stream>>>(proto, p_h, p_l);

  // EM iteration 1: compensated bf16, row-major orientation.
  // S[b][c] = cls . p  (M=8192, N=512, K=1024, split-K=2)
  gemm_bt3<<<dim3(4, 64, 2), 256, 0, stream>>>(cls_h, cls_l, p_h, p_l, SP,
                                               512, 1024, 1024, 512,
                                               (size_t)8192 * 512);
  rowsoftmax_T<true><<<256, 512, 0, stream>>>(SP, SP1, rT_h, rT_l);
  // P[c][d] = sum_b r[b][c] cls[b][d]  (M=512, N=1024, K=8192, split-K=16)
  gemm_bt3<<<dim3(8, 4, 16), 256, 0, stream>>>(rT_h, rT_l, clsT_h, clsT_l, SP,
                                               1024, 8192, 8192, 512,
                                               (size_t)512 * 1024);
  reduce_normalize<<<512, 256, 0, stream>>>(SP, p_g, pT_g);

  // EM iterations 2-5: plain fp16.
  for (int it = 0; it < 4; ++it) {
    gemm_bt<false, true><<<dim3(4, 64, 2), 256, 0, stream>>>(cls_g, p_g, SP, nullptr,
                                                             512, 1024, 1024, 512,
                                                             (size_t)8192 * 512);
    rowsoftmax_T<false><<<256, 512, 0, stream>>>(SP, SP1, rT_h, nullptr);
    gemm_bt<false, true><<<dim3(8, 4, 16), 256, 0, stream>>>(rT_h, clsT_g, SP, nullptr,
                                                             1024, 8192, 8192, 512,
                                                             (size_t)512 * 1024);
    reduce_normalize<<<512, 256, 0, stream>>>(SP, p_g, pT_g);
  }

  // Final stage, all fp16: S = cls . p^T, row softmax, z = r @ p + cls.
  gemm_bt<false, true><<<dim3(4, 64, 2), 256, 0, stream>>>(cls_g, p_g, SP, nullptr,
                                                           512, 1024, 1024, 512,
                                                           (size_t)8192 * 512);
  softmax_rows<<<2048, 256, 0, stream>>>(SP, SP1, out_r, rT_h);
  gemm_bt<true, true><<<dim3(8, 64, 1), 256, 0, stream>>>(rT_h, pT_g, out_z, cls,
                                                          1024, 512, 512, 512, 0);
}

// Round 9
// 436.851 us; speedup vs baseline: 1.0786x; 1.0317x over previous
//
#include <hip/hip_runtime.h>

typedef short v8s __attribute__((ext_vector_type(8)));
typedef _Float16 v8h __attribute__((ext_vector_type(8)));
typedef float v4f __attribute__((ext_vector_type(4)));

typedef __attribute__((address_space(1))) const void* as1_void_cp;
typedef __attribute__((address_space(3))) void* as3_void_p;

__device__ __forceinline__ unsigned short f2bf(float x) {
  union { float f; unsigned int u; } v; v.f = x;
  unsigned int r = v.u + 0x7fffu + ((v.u >> 16) & 1u);
  return (unsigned short)(r >> 16);
}
__device__ __forceinline__ float bf2f(unsigned short h) {
  union { unsigned int u; float f; } v; v.u = ((unsigned int)h) << 16;
  return v.f;
}
__device__ __forceinline__ unsigned short f2h(float x) {
  _Float16 h = (_Float16)x;  // RTE
  return __builtin_bit_cast(unsigned short, h);
}

// XCD-aware bijective block swizzle (T1/m204): each XCD gets a CONTIGUOUS
// chunk of logical tiles -> shared A/B panels fetched once per XCD-L2.
struct B3 { int x, y, z; };
__device__ __forceinline__ B3 xcd_swizzle() {
  const int gx = gridDim.x, gy = gridDim.y;
  const int nwg = gx * gy * gridDim.z;
  int flat = blockIdx.x + gx * (blockIdx.y + gy * blockIdx.z);
  if ((nwg & 7) == 0) flat = (flat & 7) * (nwg >> 3) + (flat >> 3);
  B3 b;
  b.x = flat % gx;
  b.y = (flat / gx) % gy;
  b.z = flat / (gx * gy);
  return b;
}

// ---------------------------------------------------------------------------
// Plain GEMM 128x128 (fp16/bf16): used for the final z-GEMM (ADD path).
// Double-buffered LDS, counted vmcnt, XCD swizzle.
// ---------------------------------------------------------------------------
template <bool ADD, bool F16>
__global__ __launch_bounds__(256) void gemm_bt(
    const unsigned short* __restrict__ A, const unsigned short* __restrict__ B,
    float* __restrict__ C, const float* __restrict__ Cadd,
    int N, int lda, int ldb, int klen, size_t csplit) {
  __shared__ __align__(16) unsigned short As[2][128 * 64];
  __shared__ __align__(16) unsigned short Bs[2][128 * 64];
  const int tid = threadIdx.x;
  const B3 bid = xcd_swizzle();
  const int bn = bid.x * 128, bm = bid.y * 128;
  const int k0 = bid.z * klen;
  float* Cp = C + (size_t)bid.z * csplit;

  const unsigned short* ag0 = A + (size_t)(bm + (tid >> 2)) * lda + ((tid & 3) << 3) + k0;
  const unsigned short* ag1 = ag0 + (size_t)64 * lda;
  const unsigned short* bg0 = B + (size_t)(bn + (tid >> 2)) * ldb + ((tid & 3) << 3) + k0;
  const unsigned short* bg1 = bg0 + (size_t)64 * ldb;

  const int lane = tid & 63;
  const int q = lane >> 4, m15 = lane & 15;
  const int w = tid >> 6;
  const int wr = (w >> 1) * 64, wc = (w & 1) * 64;

  v4f acc[4][4];
#pragma unroll
  for (int i = 0; i < 4; ++i)
#pragma unroll
    for (int j = 0; j < 4; ++j) acc[i][j] = 0.f;

  auto stage = [&](int kk, int b) {
    unsigned short* al = As[b] + tid * 8;
    unsigned short* bl = Bs[b] + tid * 8;
    __builtin_amdgcn_global_load_lds((as1_void_cp)(ag0 + kk), (as3_void_p)al, 16, 0, 0);
    __builtin_amdgcn_global_load_lds((as1_void_cp)(ag1 + kk), (as3_void_p)(al + 2048), 16, 0, 0);
    __builtin_amdgcn_global_load_lds((as1_void_cp)(ag0 + kk + 32), (as3_void_p)(al + 4096), 16, 0, 0);
    __builtin_amdgcn_global_load_lds((as1_void_cp)(ag1 + kk + 32), (as3_void_p)(al + 6144), 16, 0, 0);
    __builtin_amdgcn_global_load_lds((as1_void_cp)(bg0 + kk), (as3_void_p)bl, 16, 0, 0);
    __builtin_amdgcn_global_load_lds((as1_void_cp)(bg1 + kk), (as3_void_p)(bl + 2048), 16, 0, 0);
    __builtin_amdgcn_global_load_lds((as1_void_cp)(bg0 + kk + 32), (as3_void_p)(bl + 4096), 16, 0, 0);
    __builtin_amdgcn_global_load_lds((as1_void_cp)(bg1 + kk + 32), (as3_void_p)(bl + 6144), 16, 0, 0);
  };

  const int nt = klen >> 6;
  stage(0, 0);
  if (nt > 1) stage(64, 1);
  for (int t = 0; t < nt; ++t) {
    if (t + 1 < nt)
      asm volatile("s_waitcnt vmcnt(8)" ::: "memory");
    else
      asm volatile("s_waitcnt vmcnt(0)" ::: "memory");
    __builtin_amdgcn_s_barrier();
    const unsigned short* Ab = As[t & 1];
    const unsigned short* Bb = Bs[t & 1];
#pragma unroll
    for (int h = 0; h < 2; ++h) {
      v8s af[4], bf[4];
#pragma unroll
      for (int i = 0; i < 4; ++i)
        af[i] = *(const v8s*)(Ab + h * 4096 + (wr + i * 16 + m15) * 32 + q * 8);
#pragma unroll
      for (int j = 0; j < 4; ++j)
        bf[j] = *(const v8s*)(Bb + h * 4096 + (wc + j * 16 + m15) * 32 + q * 8);
#pragma unroll
      for (int i = 0; i < 4; ++i)
#pragma unroll
        for (int j = 0; j < 4; ++j) {
          if constexpr (F16)
            acc[i][j] = __builtin_amdgcn_mfma_f32_16x16x32_f16(
                __builtin_bit_cast(v8h, af[i]), __builtin_bit_cast(v8h, bf[j]), acc[i][j], 0, 0, 0);
          else
            acc[i][j] = __builtin_amdgcn_mfma_f32_16x16x32_bf16(af[i], bf[j], acc[i][j], 0, 0, 0);
        }
    }
    if (t + 2 < nt) {
      __builtin_amdgcn_s_barrier();
      stage((t + 2) << 6, t & 1);
    }
  }

#pragma unroll
  for (int i = 0; i < 4; ++i) {
#pragma unroll
    for (int j = 0; j < 4; ++j) {
      const int col = bn + wc + j * 16 + m15;
#pragma unroll
      for (int rr = 0; rr < 4; ++rr) {
        const int row = bm + wr + i * 16 + q * 4 + rr;
        const size_t idx = (size_t)row * N + col;
        float v = acc[i][j][rr];
        if (ADD) v += Cadd[idx];
        Cp[idx] = v;
      }
    }
  }
}

// ---------------------------------------------------------------------------
// NEW: fp16 GEMM with 64x128 tile (BM=64, BN=128, BK=64), 256 thr, 4 waves.
// Wave w: rows (w>>1)*32..+32, cols (w&1)*64..+64 -> acc[2][4].
// 6 global_load_lds per K-step (A:2, B:4), dbuf, vmcnt(6), XCD swizzle.
// Lets S-GEMM run split-K=1 and P-GEMM split-K=8 at full 512-block grids,
// halving split-K partial traffic vs the 128x128 versions.
// ---------------------------------------------------------------------------
__global__ __launch_bounds__(256) void gemm_bt64(
    const unsigned short* __restrict__ A, const unsigned short* __restrict__ B,
    float* __restrict__ C, int N, int lda, int ldb, int klen, size_t csplit) {
  __shared__ __align__(16) unsigned short As[2][64 * 64];    // 8 KB each
  __shared__ __align__(16) unsigned short Bs[2][128 * 64];   // 16 KB each
  const int tid = threadIdx.x;
  const B3 bid = xcd_swizzle();
  const int bn = bid.x * 128, bm = bid.y * 64;
  const int k0 = bid.z * klen;
  float* Cp = C + (size_t)bid.z * csplit;

  const unsigned short* ag0 = A + (size_t)(bm + (tid >> 2)) * lda + ((tid & 3) << 3) + k0;
  const unsigned short* bg0 = B + (size_t)(bn + (tid >> 2)) * ldb + ((tid & 3) << 3) + k0;
  const unsigned short* bg1 = bg0 + (size_t)64 * ldb;

  const int lane = tid & 63;
  const int q = lane >> 4, m15 = lane & 15;
  const int w = tid >> 6;
  const int wr = (w >> 1) * 32, wc = (w & 1) * 64;

  v4f acc[2][4];
#pragma unroll
  for (int i = 0; i < 2; ++i)
#pragma unroll
    for (int j = 0; j < 4; ++j) acc[i][j] = 0.f;

  auto stage = [&](int kk, int b) {
    unsigned short* al = As[b] + tid * 8;
    unsigned short* bl = Bs[b] + tid * 8;
    // A: [h][row(64)][col(32)] -> h stride 2048
    __builtin_amdgcn_global_load_lds((as1_void_cp)(ag0 + kk), (as3_void_p)al, 16, 0, 0);
    __builtin_amdgcn_global_load_lds((as1_void_cp)(ag0 + kk + 32), (as3_void_p)(al + 2048), 16, 0, 0);
    // B: [h][row(128)][col(32)] -> h stride 4096
    __builtin_amdgcn_global_load_lds((as1_void_cp)(bg0 + kk), (as3_void_p)bl, 16, 0, 0);
    __builtin_amdgcn_global_load_lds((as1_void_cp)(bg1 + kk), (as3_void_p)(bl + 2048), 16, 0, 0);
    __builtin_amdgcn_global_load_lds((as1_void_cp)(bg0 + kk + 32), (as3_void_p)(bl + 4096), 16, 0, 0);
    __builtin_amdgcn_global_load_lds((as1_void_cp)(bg1 + kk + 32), (as3_void_p)(bl + 6144), 16, 0, 0);
  };

  const int nt = klen >> 6;
  stage(0, 0);
  if (nt > 1) stage(64, 1);
  for (int t = 0; t < nt; ++t) {
    if (t + 1 < nt)
      asm volatile("s_waitcnt vmcnt(6)" ::: "memory");
    else
      asm volatile("s_waitcnt vmcnt(0)" ::: "memory");
    __builtin_amdgcn_s_barrier();
    const unsigned short* Ab = As[t & 1];
    const unsigned short* Bb = Bs[t & 1];
#pragma unroll
    for (int h = 0; h < 2; ++h) {
      v8s af[2], bf[4];
#pragma unroll
      for (int i = 0; i < 2; ++i)
        af[i] = *(const v8s*)(Ab + h * 2048 + (wr + i * 16 + m15) * 32 + q * 8);
#pragma unroll
      for (int j = 0; j < 4; ++j)
        bf[j] = *(const v8s*)(Bb + h * 4096 + (wc + j * 16 + m15) * 32 + q * 8);
#pragma unroll
      for (int i = 0; i < 2; ++i)
#pragma unroll
        for (int j = 0; j < 4; ++j)
          acc[i][j] = __builtin_amdgcn_mfma_f32_16x16x32_f16(
              __builtin_bit_cast(v8h, af[i]), __builtin_bit_cast(v8h, bf[j]), acc[i][j], 0, 0, 0);
    }
    if (t + 2 < nt) {
      __builtin_amdgcn_s_barrier();
      stage((t + 2) << 6, t & 1);
    }
  }

#pragma unroll
  for (int i = 0; i < 2; ++i) {
#pragma unroll
    for (int j = 0; j < 4; ++j) {
      const int col = bn + wc + j * 16 + m15;
#pragma unroll
      for (int rr = 0; rr < 4; ++rr) {
        const int row = bm + wr + i * 16 + q * 4 + rr;
        Cp[(size_t)row * N + col] = acc[i][j][rr];
      }
    }
  }
}

// ---------------------------------------------------------------------------
// Split-bf16 (compensated) GEMM: C = (Ah+Al)@(Bh+Bl)^T dropping Al*Bl.
// EM iteration 1 only. BK=32, dbuf + counted vmcnt + XCD swizzle. Unchanged.
// ---------------------------------------------------------------------------
__global__ __launch_bounds__(256) void gemm_bt3(
    const unsigned short* __restrict__ Ah, const unsigned short* __restrict__ Al,
    const unsigned short* __restrict__ Bh, const unsigned short* __restrict__ Bl,
    float* __restrict__ C, int N, int lda, int ldb, int klen, size_t csplit) {
  __shared__ __align__(16) unsigned short Ash[2][128 * 32];
  __shared__ __align__(16) unsigned short Asl[2][128 * 32];
  __shared__ __align__(16) unsigned short Bsh[2][128 * 32];
  __shared__ __align__(16) unsigned short Bsl[2][128 * 32];
  const int tid = threadIdx.x;
  const B3 bid = xcd_swizzle();
  const int bn = bid.x * 128, bm = bid.y * 128;
  const int k0 = bid.z * klen;
  float* Cp = C + (size_t)bid.z * csplit;

  const size_t aoff = (size_t)(bm + (tid >> 2)) * lda + ((tid & 3) << 3) + k0;
  const size_t boff = (size_t)(bn + (tid >> 2)) * ldb + ((tid & 3) << 3) + k0;
  const unsigned short* agh0 = Ah + aoff;
  const unsigned short* agh1 = agh0 + (size_t)64 * lda;
  const unsigned short* agl0 = Al + aoff;
  const unsigned short* agl1 = agl0 + (size_t)64 * lda;
  const unsigned short* bgh0 = Bh + boff;
  const unsigned short* bgh1 = bgh0 + (size_t)64 * ldb;
  const unsigned short* bgl0 = Bl + boff;
  const unsigned short* bgl1 = bgl0 + (size_t)64 * ldb;

  const int lane = tid & 63;
  const int q = lane >> 4, m15 = lane & 15;
  const int w = tid >> 6;
  const int wr = (w >> 1) * 64, wc = (w & 1) * 64;

  v4f acc[4][4];
#pragma unroll
  for (int i = 0; i < 4; ++i)
#pragma unroll
    for (int j = 0; j < 4; ++j) acc[i][j] = 0.f;

  auto stage = [&](int kk, int b) {
    __builtin_amdgcn_global_load_lds((as1_void_cp)(agh0 + kk), (as3_void_p)(Ash[b] + tid * 8), 16, 0, 0);
    __builtin_amdgcn_global_load_lds((as1_void_cp)(agh1 + kk), (as3_void_p)(Ash[b] + 2048 + tid * 8), 16, 0, 0);
    __builtin_amdgcn_global_load_lds((as1_void_cp)(agl0 + kk), (as3_void_p)(Asl[b] + tid * 8), 16, 0, 0);
    __builtin_amdgcn_global_load_lds((as1_void_cp)(agl1 + kk), (as3_void_p)(Asl[b] + 2048 + tid * 8), 16, 0, 0);
    __builtin_amdgcn_global_load_lds((as1_void_cp)(bgh0 + kk), (as3_void_p)(Bsh[b] + tid * 8), 16, 0, 0);
    __builtin_amdgcn_global_load_lds((as1_void_cp)(bgh1 + kk), (as3_void_p)(Bsh[b] + 2048 + tid * 8), 16, 0, 0);
    __builtin_amdgcn_global_load_lds((as1_void_cp)(bgl0 + kk), (as3_void_p)(Bsl[b] + tid * 8), 16, 0, 0);
    __builtin_amdgcn_global_load_lds((as1_void_cp)(bgl1 + kk), (as3_void_p)(Bsl[b] + 2048 + tid * 8), 16, 0, 0);
  };

  const int nt = klen >> 5;
  stage(0, 0);
  if (nt > 1) stage(32, 1);
  for (int t = 0; t < nt; ++t) {
    if (t + 1 < nt)
      asm volatile("s_waitcnt vmcnt(8)" ::: "memory");
    else
      asm volatile("s_waitcnt vmcnt(0)" ::: "memory");
    __builtin_amdgcn_s_barrier();
    const int b = t & 1;
    v8s afh[4], afl[4], bfh[4], bfl[4];
#pragma unroll
    for (int i = 0; i < 4; ++i) {
      const int ro = (wr + i * 16 + m15) * 32 + q * 8;
      afh[i] = *(const v8s*)(Ash[b] + ro);
      afl[i] = *(const v8s*)(Asl[b] + ro);
    }
#pragma unroll
    for (int j = 0; j < 4; ++j) {
      const int ro = (wc + j * 16 + m15) * 32 + q * 8;
      bfh[j] = *(const v8s*)(Bsh[b] + ro);
      bfl[j] = *(const v8s*)(Bsl[b] + ro);
    }
#pragma unroll
    for (int i = 0; i < 4; ++i)
#pragma unroll
      for (int j = 0; j < 4; ++j) {
        acc[i][j] = __builtin_amdgcn_mfma_f32_16x16x32_bf16(afh[i], bfh[j], acc[i][j], 0, 0, 0);
        acc[i][j] = __builtin_amdgcn_mfma_f32_16x16x32_bf16(afh[i], bfl[j], acc[i][j], 0, 0, 0);
        acc[i][j] = __builtin_amdgcn_mfma_f32_16x16x32_bf16(afl[i], bfh[j], acc[i][j], 0, 0, 0);
      }
    if (t + 2 < nt) {
      __builtin_amdgcn_s_barrier();
      stage((t + 2) << 5, b);
    }
  }

#pragma unroll
  for (int i = 0; i < 4; ++i) {
#pragma unroll
    for (int j = 0; j < 4; ++j) {
      const int col = bn + wc + j * 16 + m15;
#pragma unroll
      for (int rr = 0; rr < 4; ++rr) {
        const int row = bm + wr + i * 16 + q * 4 + rr;
        Cp[(size_t)row * N + col] = acc[i][j][rr];
      }
    }
  }
}

// cls f32 [8192][1024] -> hi/lo bf16 (row + transposed) AND fp16 (row +
// transposed), one pass. fp16 = f2h(hi+lo).
__global__ __launch_bounds__(256) void cast_split_transpose_cls(
    const float* __restrict__ cls,
    unsigned short* __restrict__ ch, unsigned short* __restrict__ cl,
    unsigned short* __restrict__ cTh, unsigned short* __restrict__ cTl,
    unsigned short* __restrict__ cg, unsigned short* __restrict__ cTg) {
  __shared__ unsigned short th[64][72];
  __shared__ unsigned short tl[64][72];
  const int d0 = blockIdx.x * 64, b0 = blockIdx.y * 64;
  const int t = threadIdx.x;
#pragma unroll
  for (int i = 0; i < 4; ++i) {
    int flat = t + i * 256;
    int bl_ = flat >> 4;
    int dl = (flat & 15) << 2;
    float4 v = *(const float4*)(cls + (size_t)(b0 + bl_) * 1024 + d0 + dl);
    ushort4 h, l, g;
    h.x = f2bf(v.x); l.x = f2bf(v.x - bf2f(h.x)); g.x = f2h(bf2f(h.x) + bf2f(l.x));
    h.y = f2bf(v.y); l.y = f2bf(v.y - bf2f(h.y)); g.y = f2h(bf2f(h.y) + bf2f(l.y));
    h.z = f2bf(v.z); l.z = f2bf(v.z - bf2f(h.z)); g.z = f2h(bf2f(h.z) + bf2f(l.z));
    h.w = f2bf(v.w); l.w = f2bf(v.w - bf2f(h.w)); g.w = f2h(bf2f(h.w) + bf2f(l.w));
    *(ushort4*)(ch + (size_t)(b0 + bl_) * 1024 + d0 + dl) = h;
    *(ushort4*)(cl + (size_t)(b0 + bl_) * 1024 + d0 + dl) = l;
    *(ushort4*)(cg + (size_t)(b0 + bl_) * 1024 + d0 + dl) = g;
    th[bl_][dl] = h.x; th[bl_][dl + 1] = h.y; th[bl_][dl + 2] = h.z; th[bl_][dl + 3] = h.w;
    tl[bl_][dl] = l.x; tl[bl_][dl + 1] = l.y; tl[bl_][dl + 2] = l.z; tl[bl_][dl + 3] = l.w;
  }
  __syncthreads();
#pragma unroll
  for (int i = 0; i < 4; ++i) {
    int flat = t + i * 256;
    int dl = flat >> 4;
    int bl_ = (flat & 15) << 2;
    ushort4 h = make_ushort4(th[bl_][dl], th[bl_ + 1][dl], th[bl_ + 2][dl], th[bl_ + 3][dl]);
    ushort4 l = make_ushort4(tl[bl_][dl], tl[bl_ + 1][dl], tl[bl_ + 2][dl], tl[bl_ + 3][dl]);
    ushort4 g;
    g.x = f2h(bf2f(h.x) + bf2f(l.x));
    g.y = f2h(bf2f(h.y) + bf2f(l.y));
    g.z = f2h(bf2f(h.z) + bf2f(l.z));
    g.w = f2h(bf2f(h.w) + bf2f(l.w));
    *(ushort4*)(cTh + (size_t)(d0 + dl) * 8192 + b0 + bl_) = h;
    *(ushort4*)(cTl + (size_t)(d0 + dl) * 8192 + b0 + bl_) = l;
    *(ushort4*)(cTg + (size_t)(d0 + dl) * 8192 + b0 + bl_) = g;
  }
}

// f32 -> hi/lo bf16
__global__ __launch_bounds__(256) void split_f32(const float* __restrict__ in,
                                                 unsigned short* __restrict__ hi,
                                                 unsigned short* __restrict__ lo) {
  const size_t i = (size_t)(blockIdx.x * blockDim.x + threadIdx.x) * 4;
  float4 v = *(const float4*)(in + i);
  ushort4 h, l;
  h.x = f2bf(v.x); l.x = f2bf(v.x - bf2f(h.x));
  h.y = f2bf(v.y); l.y = f2bf(v.y - bf2f(h.y));
  h.z = f2bf(v.z); l.z = f2bf(v.z - bf2f(h.z));
  h.w = f2bf(v.w); l.w = f2bf(v.w - bf2f(h.w));
  *(ushort4*)(hi + i) = h;
  *(ushort4*)(lo + i) = l;
}

// ---------------------------------------------------------------------------
// Fused row-softmax + transpose. SPLIT: S is SP0+SP1 (split-K partials);
// else SP0 only. HILO: bf16 hi/lo outputs (iter 1) vs fp16.
// ---------------------------------------------------------------------------
template <bool HILO, bool SPLIT>
__global__ __launch_bounds__(512) void rowsoftmax_T(
    const float* __restrict__ SP0, const float* __restrict__ SP1,
    unsigned short* __restrict__ rTh, unsigned short* __restrict__ rTl) {
  __shared__ __align__(16) unsigned short th[32 * 520];
  __shared__ __align__(16) unsigned short tl[HILO ? 32 * 520 : 8];
  const int t = threadIdx.x;
  const int lane = t & 63, w = t >> 6;
  const int b0 = blockIdx.x * 32;
#pragma unroll
  for (int k = 0; k < 4; ++k) {
    const int bl = w * 4 + k;
    const int row = b0 + bl;
    const size_t off = (size_t)row * 512 + lane * 8;
    float4 v0 = *(const float4*)(SP0 + off);
    float4 v1 = *(const float4*)(SP0 + off + 4);
    float e[8];
    e[0] = v0.x; e[1] = v0.y; e[2] = v0.z; e[3] = v0.w;
    e[4] = v1.x; e[5] = v1.y; e[6] = v1.z; e[7] = v1.w;
    if constexpr (SPLIT) {
      float4 u0 = *(const float4*)(SP1 + off);
      float4 u1 = *(const float4*)(SP1 + off + 4);
      e[0] += u0.x; e[1] += u0.y; e[2] += u0.z; e[3] += u0.w;
      e[4] += u1.x; e[5] += u1.y; e[6] += u1.z; e[7] += u1.w;
    }
    float m = fmaxf(fmaxf(fmaxf(e[0], e[1]), fmaxf(e[2], e[3])),
                    fmaxf(fmaxf(e[4], e[5]), fmaxf(e[6], e[7])));
    for (int o = 32; o; o >>= 1) m = fmaxf(m, __shfl_xor(m, o));
    float s = 0.f;
#pragma unroll
    for (int i = 0; i < 8; ++i) { e[i] = __expf(e[i] - m); s += e[i]; }
    for (int o = 32; o; o >>= 1) s += __shfl_xor(s, o);
    const float inv = 1.f / s;
    unsigned short ph[8], pl[8];
#pragma unroll
    for (int i = 0; i < 8; ++i) {
      const float r = e[i] * inv;
      if constexpr (HILO) {
        ph[i] = f2bf(r);
        pl[i] = f2bf(r - bf2f(ph[i]));
      } else {
        ph[i] = f2h(r);
      }
    }
    *(v8s*)&th[bl * 520 + lane * 8] = *(v8s*)ph;
    if constexpr (HILO) *(v8s*)&tl[bl * 520 + lane * 8] = *(v8s*)pl;
  }
  __syncthreads();
  const int c = t;
  unsigned short uh[32];
#pragma unroll
  for (int b = 0; b < 32; ++b) uh[b] = th[b * 520 + c];
#pragma unroll
  for (int q = 0; q < 4; ++q)
    *(v8s*)(rTh + (size_t)c * 8192 + b0 + q * 8) = *(v8s*)&uh[q * 8];
  if constexpr (HILO) {
    unsigned short ul[32];
#pragma unroll
    for (int b = 0; b < 32; ++b) ul[b] = tl[b * 520 + c];
#pragma unroll
    for (int q = 0; q < 4; ++q)
      *(v8s*)(rTl + (size_t)c * 8192 + b0 + q * 8) = *(v8s*)&ul[q * 8];
  }
}

// Final: row softmax of S [8192][512] (non-split) -> r f32 + r fp16 row-major.
__global__ __launch_bounds__(256) void softmax_rows(const float* __restrict__ SP0,
                                                    float* __restrict__ r_out,
                                                    unsigned short* __restrict__ r_g) {
  const int w = threadIdx.x >> 6, lane = threadIdx.x & 63;
  const int row = blockIdx.x * 4 + w;
  const size_t off = (size_t)row * 512 + lane * 8;
  float4 v0 = *(const float4*)(SP0 + off);
  float4 v1 = *(const float4*)(SP0 + off + 4);
  float m = fmaxf(fmaxf(fmaxf(v0.x, v0.y), fmaxf(v0.z, v0.w)),
                  fmaxf(fmaxf(v1.x, v1.y), fmaxf(v1.z, v1.w)));
  for (int off2 = 32; off2; off2 >>= 1) m = fmaxf(m, __shfl_xor(m, off2));
  float e0 = __expf(v0.x - m), e1 = __expf(v0.y - m), e2 = __expf(v0.z - m), e3 = __expf(v0.w - m);
  float e4 = __expf(v1.x - m), e5 = __expf(v1.y - m), e6 = __expf(v1.z - m), e7 = __expf(v1.w - m);
  float s = e0 + e1 + e2 + e3 + e4 + e5 + e6 + e7;
  for (int off2 = 32; off2; off2 >>= 1) s += __shfl_xor(s, off2);
  const float inv = 1.f / s;
  e0 *= inv; e1 *= inv; e2 *= inv; e3 *= inv; e4 *= inv; e5 *= inv; e6 *= inv; e7 *= inv;
  float* rp = r_out + off;
  *(float4*)rp = make_float4(e0, e1, e2, e3);
  *(float4*)(rp + 4) = make_float4(e4, e5, e6, e7);
  unsigned short* bp = r_g + off;
  *(ushort4*)bp = make_ushort4(f2h(e0), f2h(e1), f2h(e2), f2h(e3));
  *(ushort4*)(bp + 4) = make_ushort4(f2h(e4), f2h(e5), f2h(e6), f2h(e7));
}

// Sum NS split-K partials [512][1024], L2-normalize rows (+1e-6),
// emit p fp16 [512][1024] + pT fp16 [1024][512].
template <int NS>
__global__ __launch_bounds__(256) void reduce_normalize(const float* __restrict__ Pp,
                                                        unsigned short* __restrict__ pg,
                                                        unsigned short* __restrict__ pTg) {
  __shared__ float red[4];
  const int c = blockIdx.x, t = threadIdx.x;
  float ax = 0.f, ay = 0.f, az = 0.f, aw = 0.f;
#pragma unroll
  for (int s = 0; s < NS; ++s) {
    const float4 v = *(const float4*)(Pp + ((size_t)s * 512 + c) * 1024 + t * 4);
    ax += v.x; ay += v.y; az += v.z; aw += v.w;
  }
  float ss = ax * ax + ay * ay + az * az + aw * aw;
  for (int off = 32; off; off >>= 1) ss += __shfl_xor(ss, off);
  const int w = t >> 6, lane = t & 63;
  if (!lane) red[w] = ss;
  __syncthreads();
  const float tot = red[0] + red[1] + red[2] + red[3];
  const float scale = 1.f / (sqrtf(tot) + 1e-6f);
  ax *= scale; ay *= scale; az *= scale; aw *= scale;
  *(ushort4*)(pg + (size_t)c * 1024 + t * 4) =
      make_ushort4(f2h(ax), f2h(ay), f2h(az), f2h(aw));
  pTg[(size_t)(t * 4 + 0) * 512 + c] = f2h(ax);
  pTg[(size_t)(t * 4 + 1) * 512 + c] = f2h(ay);
  pTg[(size_t)(t * 4 + 2) * 512 + c] = f2h(az);
  pTg[(size_t)(t * 4 + 3) * 512 + c] = f2h(aw);
}

extern "C" void kernel_launch(void* const* d_in, const int* in_sizes, int n_in,
                              void* d_out, int out_size, void* d_ws, size_t ws_size,
                              hipStream_t stream) {
  const float* cls = (const float*)d_in[0];     // [8192,1024]
  const float* proto = (const float*)d_in[1];   // [512,1024]
  float* out_r = (float*)d_out;                 // [8192,512]
  float* out_z = out_r + (size_t)8192 * 512;    // [8192,1024]

  char* w = (char*)d_ws;
  unsigned short* cls_h = (unsigned short*)w; w += (size_t)8192 * 1024 * 2;  // 16 MB
  unsigned short* cls_l = (unsigned short*)w; w += (size_t)8192 * 1024 * 2;  // 16 MB
  unsigned short* clsT_h = (unsigned short*)w; w += (size_t)1024 * 8192 * 2; // 16 MB
  unsigned short* clsT_l = (unsigned short*)w; w += (size_t)1024 * 8192 * 2; // 16 MB
  unsigned short* cls_g = (unsigned short*)w; w += (size_t)8192 * 1024 * 2;  // 16 MB (fp16)
  unsigned short* clsT_g = (unsigned short*)w; w += (size_t)1024 * 8192 * 2; // 16 MB (fp16)
  unsigned short* p_h = (unsigned short*)w; w += (size_t)512 * 1024 * 2;     //  1 MB
  unsigned short* p_l = (unsigned short*)w; w += (size_t)512 * 1024 * 2;     //  1 MB
  unsigned short* p_g = (unsigned short*)w; w += (size_t)512 * 1024 * 2;     //  1 MB (fp16)
  unsigned short* pT_g = (unsigned short*)w; w += (size_t)1024 * 512 * 2;    //  1 MB (fp16)
  unsigned short* rT_h = (unsigned short*)w; w += (size_t)512 * 8192 * 2;    //  8 MB (also fp16 r)
  unsigned short* rT_l = (unsigned short*)w; w += (size_t)512 * 8192 * 2;    //  8 MB
  float* SP = (float*)w;  // 32 MB: [2][8192][512] / [16][512][1024]
  float* SP1 = SP + (size_t)8192 * 512;

  // One-pass cast: bf16 hi/lo (row + T) for iter-1 and fp16 (row + T).
  cast_split_transpose_cls<<<dim3(16, 128), 256, 0, stream>>>(
      cls, cls_h, cls_l, clsT_h, clsT_l, cls_g, clsT_g);
  split_f32<<<512, 256, 0, stream>>>(proto, p_h, p_l);

  // EM iteration 1: compensated bf16 (unchanged, split-K 2 / 16).
  gemm_bt3<<<dim3(4, 64, 2), 256, 0, stream>>>(cls_h, cls_l, p_h, p_l, SP,
                                               512, 1024, 1024, 512,
                                               (size_t)8192 * 512);
  rowsoftmax_T<true, true><<<256, 512, 0, stream>>>(SP, SP1, rT_h, rT_l);
  gemm_bt3<<<dim3(8, 4, 16), 256, 0, stream>>>(rT_h, rT_l, clsT_h, clsT_l, SP,
                                               1024, 8192, 8192, 512,
                                               (size_t)512 * 1024);
  reduce_normalize<16><<<512, 256, 0, stream>>>(SP, p_g, pT_g);

  // EM iterations 2-5: fp16, 64x128 tiles.
  // S: M=8192 N=512 K=1024, split-K=1, grid (4,128,1) -> SP written once.
  // P: M=512 N=1024 K=8192, split-K=8, grid (8,8,8) -> 16 MB partials.
  for (int it = 0; it < 4; ++it) {
    gemm_bt64<<<dim3(4, 128, 1), 256, 0, stream>>>(cls_g, p_g, SP,
                                                   512, 1024, 1024, 1024, 0);
    rowsoftmax_T<false, false><<<256, 512, 0, stream>>>(SP, nullptr, rT_h, nullptr);
    gemm_bt64<<<dim3(8, 8, 8), 256, 0, stream>>>(rT_h, clsT_g, SP,
                                                 1024, 8192, 8192, 1024,
                                                 (size_t)512 * 1024);
    reduce_normalize<8><<<512, 256, 0, stream>>>(SP, p_g, pT_g);
  }

  // Final stage: S (split-K=1), row softmax -> r f32 + fp16, z = r @ p + cls.
  gemm_bt64<<<dim3(4, 128, 1), 256, 0, stream>>>(cls_g, p_g, SP,
                                                 512, 1024, 1024, 1024, 0);
  softmax_rows<<<2048, 256, 0, stream>>>(SP, out_r, rT_h);
  gemm_bt<true, true><<<dim3(8, 64, 1), 256, 0, stream>>>(rT_h, pT_g, out_z, cls,
                                                          1024, 512, 512, 512, 0);
}